// Round 2
// baseline (43.677 us; speedup 1.0000x reference)
//
#include <hip/hip_runtime.h>
#include <math.h>

// Problem constants (from setup_inputs)
#define B_  16
#define A_  3
#define H_  76
#define W_  76
#define C_  80
#define T_  32
#define N_TGT (B_*T_)            // 512
#define CELLS (B_*A_*H_*W_)      // 277248
#define BITWORDS ((CELLS + 31) / 32)   // 8664 words = 34656 B LDS bitmap
#define G_  256                  // blocks in noobj kernel
#define IGNORE_THRES_ 0.5f
#define EPS_BCE_ 1e-7f

__device__ __forceinline__ float sigmoidf_(float z) { return 1.0f / (1.0f + expf(-z)); }
__device__ __forceinline__ float smooth_l1_(float d) {
    d = fabsf(d);
    return (d < 1.0f) ? 0.5f * d * d : d - 0.5f;
}
__device__ __forceinline__ float noobj_term_(float z) {
    float pc = sigmoidf_(z);
    pc = fminf(fmaxf(pc, EPS_BCE_), 1.0f - EPS_BCE_);
    return -logf(1.0f - pc);
}

// ---------------------------------------------------------------------------
// Kernel T: one block, 512 threads (one per target).
//  - per-target: anchor IoU, best anchor, LDS bitmap of (mask|conf_zero) cells
//  - last-write-wins winner detection via shared-mem keys
//  - gathered losses (x,y,w,h, obj BCE, class CE), n_correct (all targets)
//  - bitmap scan: subtracts flagged cells' noobj terms (sub_term, sub_count)
//  - zeroes the done-counter for kernel 2 (stream-ordered before it)
// acc: [0..3]=lx,ly,lw,lh [4]=obj [5]=ce [6]=nM [7]=n_correct
//      [8]=sub_term [9]=sub_count
// ---------------------------------------------------------------------------
__global__ __launch_bounds__(512) void ktargets(
    const float* __restrict__ xreg, const float* __restrict__ xcls,
    const float* __restrict__ tgt, const float* __restrict__ anch,
    float* __restrict__ acc, unsigned int* __restrict__ done)
{
    __shared__ unsigned int s_bits[BITWORDS];
    __shared__ int s_key[N_TGT];
    __shared__ float s_red[8 * 10];

    const int t = threadIdx.x;           // 0..511 == target index
    const int b = t >> 5;                // /T_

    for (int i = t; i < BITWORDS; i += 512) s_bits[i] = 0u;
    if (t == 0) *done = 0u;

    const float* tp = tgt + t * 5;
    float gx = tp[0] * (float)W_;
    float gy = tp[1] * (float)H_;
    float gw = tp[2] * (float)W_;
    float gh = tp[3] * (float)H_;
    int cls = (int)tp[4];

    int gi = (int)floorf(gx); gi = min(max(gi, 0), W_ - 1);
    int gj = (int)floorf(gy); gj = min(max(gj, 0), H_ - 1);

    float aw0 = anch[0], ah0 = anch[1];
    float aw1 = anch[2], ah1 = anch[3];
    float aw2 = anch[4], ah2 = anch[5];

    float area = gw * gh;
    float i0 = fminf(gw, aw0) * fminf(gh, ah0);
    float iou0 = i0 / (area + aw0 * ah0 - i0 + 1e-16f);
    float i1 = fminf(gw, aw1) * fminf(gh, ah1);
    float iou1 = i1 / (area + aw1 * ah1 - i1 + 1e-16f);
    float i2 = fminf(gw, aw2) * fminf(gh, ah2);
    float iou2 = i2 / (area + aw2 * ah2 - i2 + 1e-16f);

    int best = 0; float bi = iou0;
    if (iou1 > bi) { best = 1; bi = iou1; }
    if (iou2 > bi) { best = 2; bi = iou2; }

    __syncthreads();  // bitmap zeroed

    float ious[3] = { iou0, iou1, iou2 };
    #pragma unroll
    for (int a = 0; a < A_; ++a) {
        if (a == best || ious[a] > IGNORE_THRES_) {
            int cell = ((b * A_ + a) * H_ + gj) * W_ + gi;
            atomicOr(&s_bits[cell >> 5], 1u << (cell & 31));
        }
    }
    s_key[t] = (best * H_ + gj) * W_ + gi;
    __syncthreads();

    // last-write-wins winner: no later target in same batch hits same cell
    bool winner = true;
    {
        int mykey = s_key[t];
        int hi = (b + 1) * T_;
        for (int u = t + 1; u < hi; ++u)
            if (s_key[u] == mykey) { winner = false; break; }
    }

    int cell_best = ((b * A_ + best) * H_ + gj) * W_ + gi;
    const float* rp = xreg + (size_t)cell_best * 5;
    float rx = rp[0], ry = rp[1], rw = rp[2], rh = rp[3], rc = rp[4];

    // online max/argmax/logsumexp over the 80-class row
    const float* cp = xcls + (size_t)cell_best * C_;
    float m = -INFINITY, sum = 0.0f; int am = 0;
    for (int c = 0; c < C_; ++c) {
        float v = cp[c];
        if (v > m) { sum = sum * expf(m - v) + 1.0f; m = v; am = c; }
        else       { sum += expf(v - m); }
    }
    float lse = m + logf(sum);
    bool correct = (am == cls) && (rc > 0.0f);  // sigmoid(rc)>0.5 <=> rc>0

    float wlx = 0, wly = 0, wlw = 0, wlh = 0, wobj = 0, wce = 0, wm = 0;
    if (winner) {
        float tx = gx - (float)gi;
        float ty = gy - (float)gj;
        float aw = (best == 0) ? aw0 : ((best == 1) ? aw1 : aw2);
        float ah = (best == 0) ? ah0 : ((best == 1) ? ah1 : ah2);
        wlx = smooth_l1_(sigmoidf_(rx) - tx);
        wly = smooth_l1_(sigmoidf_(ry) - ty);
        wlw = smooth_l1_(rw - logf(gw / aw + 1e-16f));
        wlh = smooth_l1_(rh - logf(gh / ah + 1e-16f));
        float pc = sigmoidf_(rc);
        pc = fminf(fmaxf(pc, EPS_BCE_), 1.0f - EPS_BCE_);
        wobj = -logf(pc);
        wce = lse - cp[cls];
        wm = 1.0f;
    }

    // bitmap scan: noobj terms of flagged cells (to subtract from the total)
    float sub_t = 0.0f, sub_c = 0.0f;
    for (int wI = t; wI < BITWORDS; wI += 512) {
        unsigned int wv = s_bits[wI];
        while (wv) {
            int bit = __ffs(wv) - 1;
            wv &= wv - 1u;
            int cell = wI * 32 + bit;
            sub_t += noobj_term_(xreg[(size_t)cell * 5 + 4]);
            sub_c += 1.0f;
        }
    }

    // deterministic reduction: shuffle tree per wave + fixed-order combine
    float vals[10] = { wlx, wly, wlw, wlh, wobj, wce, wm,
                       correct ? 1.0f : 0.0f, sub_t, sub_c };
    #pragma unroll
    for (int k = 0; k < 10; ++k) {
        float v = vals[k];
        #pragma unroll
        for (int off = 32; off > 0; off >>= 1) v += __shfl_down(v, off, 64);
        vals[k] = v;
    }
    int lane = t & 63, w = t >> 6;
    if (lane == 0) {
        #pragma unroll
        for (int k = 0; k < 10; ++k) s_red[w * 10 + k] = vals[k];
    }
    __syncthreads();
    if (t == 0) {
        #pragma unroll
        for (int k = 0; k < 10; ++k) {
            float s = 0.0f;
            for (int wv = 0; wv < 8; ++wv) s += s_red[wv * 10 + k];
            acc[k] = s;
        }
    }
}

// ---------------------------------------------------------------------------
// Kernel 2: unconditional noobj BCE sum over ALL cells (streaming reduction),
// fused final combine via last-block-done. Fully deterministic: per-block
// partials in fixed order; last block sums G_ partials in fixed order.
// ---------------------------------------------------------------------------
__global__ __launch_bounds__(256) void knoobj_final(
    const float* __restrict__ xreg, const float* __restrict__ acc,
    float* __restrict__ pn, unsigned int* __restrict__ done,
    float* __restrict__ out)
{
    float s = 0.0f;
    for (int i = blockIdx.x * 256 + threadIdx.x; i < CELLS; i += G_ * 256)
        s += noobj_term_(xreg[(size_t)i * 5 + 4]);

    #pragma unroll
    for (int off = 32; off > 0; off >>= 1) s += __shfl_down(s, off, 64);

    __shared__ float sw[4];
    __shared__ unsigned int is_last;
    int lane = threadIdx.x & 63, w = threadIdx.x >> 6;
    if (lane == 0) sw[w] = s;
    __syncthreads();
    if (threadIdx.x == 0) {
        pn[blockIdx.x] = sw[0] + sw[1] + sw[2] + sw[3];
        __threadfence();
        is_last = (atomicAdd(done, 1u) == G_ - 1) ? 1u : 0u;
    }
    __syncthreads();

    if (is_last) {
        __threadfence();
        float v = pn[threadIdx.x];  // exactly G_=256 partials
        #pragma unroll
        for (int off = 32; off > 0; off >>= 1) v += __shfl_down(v, off, 64);
        if (lane == 0) sw[w] = v;
        __syncthreads();
        if (threadIdx.x == 0) {
            float total = sw[0] + sw[1] + sw[2] + sw[3];
            float noobj_sum = total - acc[8];
            float nF = fmaxf((float)CELLS - acc[9], 1.0f);
            float nM = fmaxf(acc[6], 1.0f);
            float lx = acc[0] / nM, ly = acc[1] / nM;
            float lw = acc[2] / nM, lh = acc[3] / nM;
            float lconf = noobj_sum / nF + acc[4] / nM;
            float lcls = acc[5] / nM;
            float coord = lx + ly + lw + lh;
            out[0] = coord + lconf + lcls;
            out[1] = coord;
            out[2] = lconf;
            out[3] = lcls;
            out[4] = acc[7];  // n_correct (float32 buffer)
        }
    }
}

extern "C" void kernel_launch(void* const* d_in, const int* in_sizes, int n_in,
                              void* d_out, int out_size, void* d_ws, size_t ws_size,
                              hipStream_t stream) {
    const float* xreg = (const float*)d_in[0];
    const float* xcls = (const float*)d_in[1];
    const float* tgt  = (const float*)d_in[2];
    const float* anch = (const float*)d_in[3];
    float* out = (float*)d_out;

    char* ws = (char*)d_ws;
    float* acc = (float*)ws;                       // 16 floats
    float* pn  = (float*)(ws + 64);                // G_ floats
    unsigned int* done = (unsigned int*)(ws + 64 + G_ * 4);

    ktargets<<<1, 512, 0, stream>>>(xreg, xcls, tgt, anch, acc, done);
    knoobj_final<<<G_, 256, 0, stream>>>(xreg, acc, pn, done, out);
}